// Round 7
// baseline (430.614 us; speedup 1.0000x reference)
//
#include <hip/hip_runtime.h>

typedef __attribute__((ext_vector_type(4))) float f32x4;
typedef __attribute__((ext_vector_type(8))) short s16x8;
typedef __attribute__((ext_vector_type(2))) unsigned int u32x2;
typedef __attribute__((ext_vector_type(4))) unsigned int u32x4;

#define X_ELEMS 25690112          // 32*64*112*112
#define X_F4    6422528           // X_ELEMS/4
#define HW 112
#define PW 120                    // padded row width: 4 zero cols left, 4 right
#define PPLANE (112*120)          // 13440 shorts per padded channel plane
#define CHW (64*112*112)          // 802816

// q = I * 2^(e-7), |I|<=256 -> exactly representable in bf16; low 16 fp32 bits are 0.
__device__ __forceinline__ unsigned short f32_to_bf16_exact(float q) {
    return (unsigned short)(__float_as_uint(q) >> 16);
}

// pack bf16(a) into low short, bf16(b) into high short (one v_perm_b32)
__device__ __forceinline__ unsigned int pack_bf16x2(float a, float b) {
    return __builtin_amdgcn_perm(__float_as_uint(b), __float_as_uint(a), 0x07060302u);
}

__device__ __forceinline__ void scale_from_max(float m, float& scale, float& inv) {
    if (m > 0.f) {
        int e = (int)((__float_as_uint(m) >> 23) & 0xFF) - 127;  // exact floor(log2(m)) for normal m
        scale = __builtin_ldexpf(1.0f, e - 7);
        inv   = __builtin_ldexpf(1.0f, 7 - e);
    } else { scale = 0.f; inv = 0.f; }
}

// ---- Q1 (fused): read x ONCE, group-max via LDS, quantize in-register,
// write xq = bf16 NCHW with row padding [plane][112][120] (pad cols zeroed).
// All stores 8B-aligned (left pad = 4 shorts). Block 2788 quantizes weights. ----
__global__ __launch_bounds__(256) void q1_quant(const float* __restrict__ x,
                                                const float* __restrict__ w,
                                                unsigned short* __restrict__ xq,
                                                unsigned short* __restrict__ wt) {
    __shared__ float lmax[2304];
    __shared__ float lsc[256];
    __shared__ float linv[256];
    const int b = blockIdx.x, tid = threadIdx.x;

    if (b == 2788) {                              // ---- weight path: 1024 groups of 36
        #pragma unroll 1
        for (int rep = 0; rep < 4; ++rep) {
            int g = rep * 256 + tid;
            const float4* p = (const float4*)w + g * 9;
            float vv[36]; float m = 0.f;
            #pragma unroll
            for (int i = 0; i < 9; ++i) {
                float4 v = p[i];
                vv[i*4+0]=v.x; vv[i*4+1]=v.y; vv[i*4+2]=v.z; vv[i*4+3]=v.w;
                m = fmaxf(m, fmaxf(fmaxf(fabsf(v.x), fabsf(v.y)), fmaxf(fabsf(v.z), fabsf(v.w))));
            }
            float s, inv; scale_from_max(m, s, inv);
            #pragma unroll
            for (int j = 0; j < 36; ++j) {
                int flat = g * 36 + j;
                int k = flat / 576, rem = flat % 576;
                int c = rem / 9, pp = rem % 9;
                float q = rintf(vv[j] * inv) * s;
                wt[pp * 4096 + k * 64 + c] = f32_to_bf16_exact(q);
            }
        }
        return;
    }

    // ---- x path: block owns 256 groups = 9216 floats = 2304 float4 (contiguous)
    long base4 = (long)b * 2304;
    float4 vv[9];
    #pragma unroll
    for (int it = 0; it < 9; ++it) {
        int i = it * 256 + tid;
        long g4 = base4 + i;
        float4 v = {0.f, 0.f, 0.f, 0.f};
        if (g4 < X_F4) v = ((const float4*)x)[g4];
        vv[it] = v;
        lmax[i] = fmaxf(fmaxf(fabsf(v.x), fabsf(v.y)), fmaxf(fabsf(v.z), fabsf(v.w)));
    }
    __syncthreads();
    {
        float m = 0.f; int o = tid * 9;           // stride-9 over 32 banks: conflict-light
        #pragma unroll
        for (int j = 0; j < 9; ++j) m = fmaxf(m, lmax[o + j]);
        float s, inv; scale_from_max(m, s, inv);
        lsc[tid] = s; linv[tid] = inv;
    }
    __syncthreads();
    #pragma unroll
    for (int it = 0; it < 9; ++it) {
        int i = it * 256 + tid;
        int g4 = (int)base4 + i;
        if (g4 < X_F4) {
            int lg = i / 9;                       // float4 never crosses a group (36 % 4 == 0)
            float s = lsc[lg], inv = linv[lg];
            float4 v = vv[it];
            u32x2 o;
            o.x = pack_bf16x2(rintf(v.x * inv) * s, rintf(v.y * inv) * s);
            o.y = pack_bf16x2(rintf(v.z * inv) * s, rintf(v.w * inv) * s);
            int flat = g4 * 4;                    // NCHW element index (w % 4 == 0, 112 % 4 == 0)
            int plane = flat / 12544;
            int rw = flat - plane * 12544;
            int h = rw / 112, ww = rw - h * 112;
            int rowb = plane * PPLANE + h * PW;
            *(u32x2*)(xq + rowb + 4 + ww) = o;    // 8B store, 8B-aligned
            if (ww == 0)        *(u32x2*)(xq + rowb) = (u32x2){0u, 0u};        // pad cols 0-3
            else if (ww == 108) *(u32x2*)(xq + rowb + 116) = (u32x2){0u, 0u};  // pad cols 116-119
        }
    }
}

// LDS address with XOR-swizzled 16B c-octet slot: bank cluster = f(pix, oct) covers
// all 8 clusters across a wave (plain layout collapses to 2 -> ~4x conflict).
__device__ __forceinline__ int swz(int pix, int oct) {
    return pix * 72 + (((oct) ^ ((pix >> 3) & 7)) << 3);
}

__device__ __forceinline__ void tile_decode(int st, int& n, int& h0, int& w0) {
    n = st / 56; int rem = st - n * 56;
    h0 = (rem >> 2) * 8; w0 = (rem & 3) * 28;
}

// staging task t in [0,320): (c-octet 8) x (row 10) x (w-oct 4).
// load half: 8 b128 (8 channels x 8 w) from padded-NCHW xq into regs.
__device__ __forceinline__ void regload_task(const unsigned short* __restrict__ xq,
                                             int n, int h0, int w0, int t, u32x4 v[8]) {
    int oct = t / 40;
    int rm = t - oct * 40;
    int r = rm >> 2, wq = rm & 3;
    int hh = h0 - 1 + r;
    int c0 = w0 + 2 + wq * 8;                     // padded col of data col (w0-2 + wq*8)
    if (hh >= 0 && hh < HW) {
        const unsigned short* src = xq + (n * 64 + oct * 8) * PPLANE + hh * PW + c0;
        #pragma unroll
        for (int j = 0; j < 8; ++j)
            v[j] = *(const u32x4*)(src + j * PPLANE);
    } else {
        #pragma unroll
        for (int j = 0; j < 8; ++j) v[j] = (u32x4){0u, 0u, 0u, 0u};
    }
}

// write half: 8x8 register transpose (32 perms), 8 ds_write_b128 at swizzled slots.
__device__ __forceinline__ void permwrite_task(unsigned short* xs, int t, u32x4 v[8]) {
    int oct = t / 40;
    int rm = t - oct * 40;
    int r = rm >> 2, wq = rm & 3;
    int pix0 = r * 36 + wq * 8 + 2;               // halo cols 2..33 (reads touch 3..32)
    #pragma unroll
    for (int d = 0; d < 8; ++d) {
        unsigned int sel = (d & 1) ? 0x07060302u : 0x05040100u;
        int k = d >> 1;
        u32x4 o;
        o.x = __builtin_amdgcn_perm(v[1][k], v[0][k], sel);
        o.y = __builtin_amdgcn_perm(v[3][k], v[2][k], sel);
        o.z = __builtin_amdgcn_perm(v[5][k], v[4][k], sel);
        o.w = __builtin_amdgcn_perm(v[7][k], v[6][k], sel);
        *(u32x4*)&xs[swz(pix0 + d, oct)] = o;
    }
}

// ---- conv: PERSISTENT blocks. Grid 512 (2/CU, all resident, no re-launch).
// Block bs<256: tiles {bs, bs+512, bs+1024, 1536+bs}; bs>=256: first three.
// Exact cover of 1792 tiles; all of a block's tiles share t&7 (same XCD chunk).
// Per tile: regs for tile i+1 are LOADED before COMPUTE(i) (T14 async-split:
// ~500-900cyc L3 latency hides under the ~3-4K-cycle MFMA phase); the
// perm+ds_write lands between two barriers after the stores. ----
__global__ __launch_bounds__(256, 2) void conv_mfma(const unsigned short* __restrict__ xq,
                                                    const unsigned short* __restrict__ wt,
                                                    const float* __restrict__ bias,
                                                    float* __restrict__ out) {
    __shared__ unsigned short xs[360 * 72];       // 10 rows x 36 cols halo, 72-short pixel stride
    const int tid = threadIdx.x;
    const int wave = tid >> 6, lane = tid & 63;
    const int wl = lane & 15, quad = lane >> 4;
    const int kg = wave & 1, mg = wave >> 1;
    const int bs = blockIdx.x;
    const int nt = (bs < 256) ? 4 : 3;
    const bool has1 = (tid < 64);                 // wave 0 carries the 64 extra staging tasks

    // tile-independent per-wave state (compiler sinks B loads into the p-loop; wt is L2-hot)
    s16x8 Bf[9][2][2];
    #pragma unroll
    for (int p = 0; p < 9; ++p)
        #pragma unroll
        for (int cs = 0; cs < 2; ++cs)
            #pragma unroll
            for (int j = 0; j < 2; ++j)
                Bf[p][cs][j] = *(const s16x8*)(wt + p * 4096 +
                                ((kg * 2 + j) * 16 + wl) * 64 + cs * 32 + quad * 8);
    float bv[2];
    #pragma unroll
    for (int j = 0; j < 2; ++j) bv[j] = bias[kg * 32 + j * 16 + wl];
    int pixb[7];
    #pragma unroll
    for (int mti = 0; mti < 7; ++mti) {
        int m = (mg * 7 + mti) * 16 + wl;
        pixb[mti] = (m / 28) * 36 + (m % 28) + 3;           // col offset +3 in 36-wide halo
    }

    u32x4 v0[8], v1[8];
    {   // prologue: stage tile 0
        int t0 = bs;
        int st = ((t0 & 7) * 224) + (t0 >> 3);    // XCD-chunked tile swizzle (bijective)
        int n, h0, w0; tile_decode(st, n, h0, w0);
        regload_task(xq, n, h0, w0, tid, v0);
        if (has1) regload_task(xq, n, h0, w0, 256 + tid, v1);
        permwrite_task(xs, tid, v0);
        if (has1) permwrite_task(xs, 256 + tid, v1);
    }
    __syncthreads();

    #pragma unroll 1
    for (int i = 0; i < nt; ++i) {
        int tc = (i < 3) ? (bs + 512 * i) : (1536 + bs);
        int st = ((tc & 7) * 224) + (tc >> 3);
        int n, h0, w0; tile_decode(st, n, h0, w0);

        if (i + 1 < nt) {                         // prefetch next tile into regs (issue only)
            int tn = (i + 1 < 3) ? (bs + 512 * (i + 1)) : (1536 + bs);
            int stn = ((tn & 7) * 224) + (tn >> 3);
            int nn, hn, wn; tile_decode(stn, nn, hn, wn);
            regload_task(xq, nn, hn, wn, tid, v0);
            if (has1) regload_task(xq, nn, hn, wn, 256 + tid, v1);
        }

        f32x4 acc[7][2];
        f32x4 zero = {0.f, 0.f, 0.f, 0.f};
        #pragma unroll
        for (int mti = 0; mti < 7; ++mti) { acc[mti][0] = zero; acc[mti][1] = zero; }

        #pragma unroll
        for (int p = 0; p < 9; ++p) {
            const int dpix = (p / 3) * 36 + (p % 3);
            #pragma unroll
            for (int cs = 0; cs < 2; ++cs) {
                s16x8 A[7];
                #pragma unroll
                for (int mti = 0; mti < 7; ++mti)
                    A[mti] = *(const s16x8*)&xs[swz(pixb[mti] + dpix, cs * 4 + quad)];
                #pragma unroll
                for (int mti = 0; mti < 7; ++mti) {
                    acc[mti][0] = __builtin_amdgcn_mfma_f32_16x16x32_bf16(A[mti], Bf[p][cs][0], acc[mti][0], 0, 0, 0);
                    acc[mti][1] = __builtin_amdgcn_mfma_f32_16x16x32_bf16(A[mti], Bf[p][cs][1], acc[mti][1], 0, 0, 0);
                }
            }
        }

        // epilogue: direct coalesced float4 stores
        int obase = n * CHW + h0 * HW + w0;
        #pragma unroll
        for (int mti = 0; mti < 7; ++mti) {
            int m0 = (mg * 7 + mti) * 16 + quad * 4;        // 28%4==0 -> float4 stays in-row
            int eofs = (m0 / 28) * HW + (m0 % 28);
            #pragma unroll
            for (int j = 0; j < 2; ++j) {
                f32x4 v = acc[mti][j];
                v.x += bv[j]; v.y += bv[j]; v.z += bv[j]; v.w += bv[j];
                *(f32x4*)(out + obase + (kg * 32 + j * 16 + wl) * 12544 + eofs) = v;
            }
        }

        if (i + 1 < nt) {
            __syncthreads();                      // all waves done reading xs(tile i)
            permwrite_task(xs, tid, v0);
            if (has1) permwrite_task(xs, 256 + tid, v1);
            __syncthreads();                      // xs(tile i+1) ready
        }
    }
}

extern "C" void kernel_launch(void* const* d_in, const int* in_sizes, int n_in,
                              void* d_out, int out_size, void* d_ws, size_t ws_size,
                              hipStream_t stream) {
    const float* x    = (const float*)d_in[0];
    const float* w    = (const float*)d_in[1];
    const float* bias = (const float*)d_in[2];
    float* out = (float*)d_out;
    char* ws = (char*)d_ws;
    unsigned short* xq = (unsigned short*)ws;                   // 32*64*112*120*2 = 55,050,240 B
    unsigned short* wt = (unsigned short*)(ws + 55050240);      //     73,728 B

    hipLaunchKernelGGL(q1_quant,  dim3(2789), dim3(256), 0, stream, x, w, xq, wt);
    hipLaunchKernelGGL(conv_mfma, dim3(512),  dim3(256), 0, stream, xq, wt, bias, out);
}

// Round 8
// 273.109 us; speedup vs baseline: 1.5767x; 1.5767x over previous
//
#include <hip/hip_runtime.h>

typedef __attribute__((ext_vector_type(4))) float f32x4;
typedef __attribute__((ext_vector_type(8))) short s16x8;
typedef __attribute__((ext_vector_type(4))) unsigned int u32x4;

#define HW 112
#define PW8 116                   // padded cols in xq8 (2 left, 2 right)
#define ROWS8 (PW8*8)             // shorts per (plane,row) = 928
#define PLANE8 (112*ROWS8)        // shorts per (n,oct) plane = 103,936
#define CHW (64*112*112)          // 802816
#define NG 713615
#define X_F4 6422528

// ws byte offsets
#define XQ8_BYTES 53215232        // 32*8*PLANE8*2
#define WT_OFF    53219328        // XQ8 + 4KB slack (staging over-reads past plane end)
#define SC_OFF    53293056        // WT + 73,728
#define ZP_OFF    59001984        // SC + 5,708,920 (16B aligned); 1KB zeros

__device__ __forceinline__ unsigned short f32_to_bf16_exact(float q) {
    return (unsigned short)(__float_as_uint(q) >> 16);
}
__device__ __forceinline__ unsigned int pack_bf16x2(float a, float b) {
    return __builtin_amdgcn_perm(__float_as_uint(b), __float_as_uint(a), 0x07060302u);
}
__device__ __forceinline__ void scale_from_max(float m, float& scale, float& inv) {
    if (m > 0.f) {
        int e = (int)((__float_as_uint(m) >> 23) & 0xFF) - 127;
        scale = __builtin_ldexpf(1.0f, e - 7);
        inv   = __builtin_ldexpf(1.0f, 7 - e);
    } else { scale = 0.f; inv = 0.f; }
}

// ---- Q1: per-group (36) scales -> sc[g]=(s,inv). Block 2788: weights + zero page. ----
__global__ __launch_bounds__(256) void q1_scales(const float* __restrict__ x,
                                                 const float* __restrict__ w,
                                                 float2* __restrict__ sc,
                                                 unsigned short* __restrict__ wt,
                                                 u32x4* __restrict__ zp) {
    __shared__ float lmax[2304];
    const int b = blockIdx.x, tid = threadIdx.x;

    if (b == 2788) {                              // weights: 1024 groups of 36; zero page
        if (tid < 64) zp[tid] = (u32x4){0u, 0u, 0u, 0u};
        #pragma unroll 1
        for (int rep = 0; rep < 4; ++rep) {
            int g = rep * 256 + tid;
            const float4* p = (const float4*)w + g * 9;
            float vv[36]; float m = 0.f;
            #pragma unroll
            for (int i = 0; i < 9; ++i) {
                float4 v = p[i];
                vv[i*4+0]=v.x; vv[i*4+1]=v.y; vv[i*4+2]=v.z; vv[i*4+3]=v.w;
                m = fmaxf(m, fmaxf(fmaxf(fabsf(v.x), fabsf(v.y)), fmaxf(fabsf(v.z), fabsf(v.w))));
            }
            float s, inv; scale_from_max(m, s, inv);
            #pragma unroll
            for (int j = 0; j < 36; ++j) {
                int flat = g * 36 + j;
                int k = flat / 576, rem = flat % 576;
                int c = rem / 9, pp = rem % 9;
                float q = rintf(vv[j] * inv) * s;
                wt[pp * 4096 + k * 64 + c] = f32_to_bf16_exact(q);
            }
        }
        return;
    }

    long base4 = (long)b * 2304;                  // 256 groups = 2304 float4, contiguous
    #pragma unroll
    for (int it = 0; it < 9; ++it) {
        int i = it * 256 + tid;
        long g4 = base4 + i;
        float m = 0.f;
        if (g4 < X_F4) {
            float4 v = ((const float4*)x)[g4];
            m = fmaxf(fmaxf(fabsf(v.x), fabsf(v.y)), fmaxf(fabsf(v.z), fabsf(v.w)));
        }
        lmax[i] = m;
    }
    __syncthreads();
    int g = b * 256 + tid;
    if (g < NG) {
        float m = 0.f; int o = tid * 9;
        #pragma unroll
        for (int j = 0; j < 9; ++j) m = fmaxf(m, lmax[o + j]);
        float s, inv; scale_from_max(m, s, inv);
        sc[g] = make_float2(s, inv);
    }
}

// ---- Q2: quantize x -> xq8 in NHWC8 [n][oct][h][116w][8c], pad cols zeroed.
// Reads x coalesced (L3-hot after q1); 16B/thread coalesced writes. ----
__global__ __launch_bounds__(256) void q2_quant(const float* __restrict__ x,
                                                const float2* __restrict__ sc,
                                                unsigned short* __restrict__ xq8) {
    int blk = blockIdx.x;
    int pb = blk % 49; int t2 = blk / 49; int oct = t2 & 7; int n = t2 >> 3;
    int p = pb * 256 + threadIdx.x;               // pixel 0..12543
    int h = p / 112, ww = p - h * 112;
    unsigned short* row = xq8 + ((n * 8 + oct) * 112 + h) * ROWS8;
    int cbase = (n * 64 + oct * 8) * 12544 + p;
    unsigned int pk[4];
    #pragma unroll
    for (int jj = 0; jj < 4; ++jj) {
        int f0 = cbase + (2 * jj) * 12544;
        int f1 = f0 + 12544;
        float2 s0 = sc[(unsigned)f0 / 36u];
        float2 s1 = sc[(unsigned)f1 / 36u];
        float q0 = rintf(x[f0] * s0.y) * s0.x;
        float q1 = rintf(x[f1] * s1.y) * s1.x;
        pk[jj] = pack_bf16x2(q0, q1);
    }
    *(u32x4*)(row + (ww + 2) * 8) = (u32x4){pk[0], pk[1], pk[2], pk[3]};
    u32x4 z4 = {0u, 0u, 0u, 0u};
    if (ww == 0)        { *(u32x4*)(row) = z4;            *(u32x4*)(row + 8) = z4; }
    else if (ww == 111) { *(u32x4*)(row + 114 * 8) = z4;  *(u32x4*)(row + 115 * 8) = z4; }
}

// ---- conv: persistent, grid 256 (1 block/CU), 7 tiles/block, LDS double-buffer.
// Staging = 52x global_load_lds_dwordx4 (no VGPR hold, no perms): LDS chunk g =
// (oct, r, pix) linear, per-lane SOURCE pre-swizzled pix^oct (bank-conflict fix,
// m173 pattern). OOB rows + pad chunks read the zero page. Single barrier/tile:
// issue(i+1) after barrier(i) -> vmcnt(0) at iter i+1 is nearly free (a full
// compute phase separates issue from wait). ----
__global__ __launch_bounds__(256) void conv_mfma(const unsigned short* __restrict__ xq8,
                                                 const unsigned short* __restrict__ wt,
                                                 const float* __restrict__ bias,
                                                 float* __restrict__ out,
                                                 const unsigned short* __restrict__ zp) {
    __shared__ unsigned short xs[2][3328 * 8];    // 2 x 53,248 B
    const int tid = threadIdx.x;
    const int wave = tid >> 6, lane = tid & 63;
    const int wl = lane & 15, quad = lane >> 4;
    const int kg = wave & 1, mg = wave >> 1;
    const int bs = blockIdx.x;

    // per-slot tile-independent decode: slot k covers chunk g=(wave*13+k)*64+lane
    unsigned pk13[13];
    #pragma unroll
    for (int k = 0; k < 13; ++k) {
        int g = (wave * 13 + k) * 64 + lane;
        if (g < 3200) {
            int oct = g / 400, rem = g - oct * 400;
            int r = rem / 40, pix = rem - r * 40;
            int pixs = pix ^ oct;                 // source-side swizzle (low 3 bits)
            pk13[k] = ((unsigned)r << 24) | (unsigned)(oct * PLANE8 + pixs * 8);
        } else pk13[k] = 0xFF000000u;             // pad chunk -> zero page
    }

    float bv[2];
    #pragma unroll
    for (int j = 0; j < 2; ++j) bv[j] = bias[kg * 32 + j * 16 + wl];
    int pixb[7];
    #pragma unroll
    for (int mti = 0; mti < 7; ++mti) {
        int m = (mg * 7 + mti) * 16 + wl;
        pixb[mti] = (m / 28) * 40 + (m % 28) + 1; // row*40 + base col j (LP=2 => +1)
    }

    auto issue = [&](int ti, int bi) {
        int t = bs + 256 * ti;
        int st = ((t & 7) * 224) + (t >> 3);      // XCD-chunked swizzle
        int n = st / 56, rem = st - n * 56;
        int h0 = (rem >> 2) * 8, w0 = (rem & 3) * 28;
        const unsigned short* base = xq8 + n * 8 * PLANE8 + w0 * 8;
        #pragma unroll
        for (int k = 0; k < 13; ++k) {
            unsigned pk = pk13[k];
            int r = (int)(pk >> 24);
            int hh = h0 - 1 + r;
            bool ok = (r <= 9) && (hh >= 0) && (hh < HW);
            const unsigned short* src = ok ? (base + (pk & 0xFFFFFFu) + hh * ROWS8) : zp;
            unsigned short* dst = (unsigned short*)&xs[bi][(wave * 13 + k) * 512];
            __builtin_amdgcn_global_load_lds(
                (const __attribute__((address_space(1))) void*)src,
                (__attribute__((address_space(3))) void*)dst, 16, 0, 0);
        }
    };

    issue(0, 0);                                  // prologue: stage tile 0

    #pragma unroll 1
    for (int i = 0; i < 7; ++i) {
        asm volatile("s_waitcnt vmcnt(0)" ::: "memory");  // my gloads for buf[i&1] done
        __builtin_amdgcn_s_barrier();             // all waves' gloads done; prev readers done
        if (i < 6) issue(i + 1, (i + 1) & 1);     // prefetch next tile (hides under compute)

        int t = bs + 256 * i;
        int st = ((t & 7) * 224) + (t >> 3);
        int n = st / 56, rem = st - n * 56;
        int h0 = (rem >> 2) * 8, w0 = (rem & 3) * 28;
        const unsigned short* xb = &xs[i & 1][0];

        f32x4 acc[7][2];
        f32x4 zero = {0.f, 0.f, 0.f, 0.f};
        #pragma unroll
        for (int mti = 0; mti < 7; ++mti) { acc[mti][0] = zero; acc[mti][1] = zero; }

        #pragma unroll
        for (int p = 0; p < 9; ++p) {
            const int dpix = (p / 3) * 40 + (p % 3);
            #pragma unroll
            for (int cs = 0; cs < 2; ++cs) {
                const int oq = cs * 4 + quad;
                s16x8 B0 = *(const s16x8*)(wt + p * 4096 + ((kg * 2 + 0) * 16 + wl) * 64 + cs * 32 + quad * 8);
                s16x8 B1 = *(const s16x8*)(wt + p * 4096 + ((kg * 2 + 1) * 16 + wl) * 64 + cs * 32 + quad * 8);
                s16x8 A[7];
                #pragma unroll
                for (int mti = 0; mti < 7; ++mti) {
                    int pix = pixb[mti] + dpix;
                    A[mti] = *(const s16x8*)(xb + (oq * 400 + (pix ^ oq)) * 8);
                }
                #pragma unroll
                for (int mti = 0; mti < 7; ++mti) {
                    acc[mti][0] = __builtin_amdgcn_mfma_f32_16x16x32_bf16(A[mti], B0, acc[mti][0], 0, 0, 0);
                    acc[mti][1] = __builtin_amdgcn_mfma_f32_16x16x32_bf16(A[mti], B1, acc[mti][1], 0, 0, 0);
                }
            }
        }

        int obase = n * CHW + h0 * HW + w0;
        #pragma unroll
        for (int mti = 0; mti < 7; ++mti) {
            int m0 = (mg * 7 + mti) * 16 + quad * 4;
            int eofs = (m0 / 28) * HW + (m0 % 28);
            #pragma unroll
            for (int j = 0; j < 2; ++j) {
                f32x4 v = acc[mti][j];
                v.x += bv[j]; v.y += bv[j]; v.z += bv[j]; v.w += bv[j];
                *(f32x4*)(out + obase + (kg * 32 + j * 16 + wl) * 12544 + eofs) = v;
            }
        }
    }
}

extern "C" void kernel_launch(void* const* d_in, const int* in_sizes, int n_in,
                              void* d_out, int out_size, void* d_ws, size_t ws_size,
                              hipStream_t stream) {
    const float* x    = (const float*)d_in[0];
    const float* w    = (const float*)d_in[1];
    const float* bias = (const float*)d_in[2];
    float* out = (float*)d_out;
    char* ws = (char*)d_ws;
    unsigned short* xq8 = (unsigned short*)ws;
    unsigned short* wt  = (unsigned short*)(ws + WT_OFF);
    float2*         sc  = (float2*)(ws + SC_OFF);
    unsigned short* zp  = (unsigned short*)(ws + ZP_OFF);

    hipLaunchKernelGGL(q1_scales, dim3(2789),  dim3(256), 0, stream, x, w, sc, wt, (u32x4*)zp);
    hipLaunchKernelGGL(q2_quant,  dim3(12544), dim3(256), 0, stream, x, sc, xq8);
    hipLaunchKernelGGL(conv_mfma, dim3(256),   dim3(256), 0, stream, xq8, wt, bias, out, zp);
}